// Round 9
// baseline (48.632 us; speedup 1.0000x reference)
//
#include <hip/hip_runtime.h>

// out[m, n] = sum_d a[m, d] * T_d(x[n]),  T_d = Chebyshev via recurrence.
// N = 2097152, M = 32, DEG = 16. Write-BW-bound (~256 MiB out).
// R8: R7 store structure EXACTLY (EPT=4, float4 stores, m-ascending order,
// XCD-contiguous swizzle -> 48.3 us) + halve dot VALU via v_pk_fma_f32.
// The {c,c} coefficient broadcast uses VOP3P op_sel/op_sel_hi to replicate
// one 32-bit half of a wave-uniform SGPR pair into both lanes -- no dup
// table, no extra dispatch (R6's confound).

#define DEG 16
#define M_ROWS 32
#define ELEMS_PER_THREAD 4
#define NUM_XCD 8

typedef __attribute__((ext_vector_type(2))) float f32x2;

__global__ __launch_bounds__(256) void cheb_gemm_kernel(
    const float* __restrict__ x,
    const float* __restrict__ a,
    float* __restrict__ out,
    int n)
{
    // Bijective XCD swizzle (gridDim.x % 8 == 0): each XCD owns a contiguous
    // slice of the n-dimension (R7: +6%).
    const int per_xcd = gridDim.x >> 3;               // 256
    const int chunk = (blockIdx.x & (NUM_XCD - 1)) * per_xcd
                    + (blockIdx.x >> 3);
    const int i = (chunk * 256 + threadIdx.x) * ELEMS_PER_THREAD;
    if (i + ELEMS_PER_THREAD - 1 >= n) return;

    const float4 xv = *reinterpret_cast<const float4*>(x + i);

    // Basis pairs: bA[d] = {T_d(x0), T_d(x1)}, bB[d] = {T_d(x2), T_d(x3)}.
    // f32x2 arithmetic -> compiler emits v_pk_fma_f32 (verified in R6).
    f32x2 bA[DEG], bB[DEG];
    {
        f32x2 xA; xA.x = xv.x; xA.y = xv.y;
        f32x2 xB; xB.x = xv.z; xB.y = xv.w;
        f32x2 one; one.x = 1.0f; one.y = 1.0f;
        bA[0] = one; bB[0] = one;
        bA[1] = xA;  bB[1] = xB;
        const f32x2 txA = xA + xA;
        const f32x2 txB = xB + xB;
#pragma unroll
        for (int k = 2; k < DEG; ++k) {
            bA[k] = txA * bA[k - 1] - bA[k - 2];
            bB[k] = txB * bB[k - 1] - bB[k - 2];
        }
    }

    // Per m-row: packed dot. Coefficients load as natural {a[2k],a[2k+1]}
    // SGPR pairs; op_sel broadcasts one half into both lanes.
#pragma unroll 4
    for (int m = 0; m < M_ROWS; ++m) {
        const float* am = a + m * DEG;  // wave-uniform
        f32x2 accA, accB;
        {
            const f32x2 c01 = *reinterpret_cast<const f32x2*>(am);
            // d=0: broadcast LO half of c01
            asm("v_pk_mul_f32 %0, %1, %2 op_sel:[0,0] op_sel_hi:[0,1]"
                : "=v"(accA) : "s"(c01), "v"(bA[0]));
            asm("v_pk_mul_f32 %0, %1, %2 op_sel:[0,0] op_sel_hi:[0,1]"
                : "=v"(accB) : "s"(c01), "v"(bB[0]));
            // d=1: broadcast HI half of c01
            asm("v_pk_fma_f32 %0, %1, %2, %0 op_sel:[1,0,0] op_sel_hi:[1,1,1]"
                : "+v"(accA) : "s"(c01), "v"(bA[1]));
            asm("v_pk_fma_f32 %0, %1, %2, %0 op_sel:[1,0,0] op_sel_hi:[1,1,1]"
                : "+v"(accB) : "s"(c01), "v"(bB[1]));
        }
#pragma unroll
        for (int k = 1; k < DEG / 2; ++k) {
            const f32x2 cp = *reinterpret_cast<const f32x2*>(am + 2 * k);
            // even d = 2k: broadcast LO
            asm("v_pk_fma_f32 %0, %1, %2, %0 op_sel:[0,0,0] op_sel_hi:[0,1,1]"
                : "+v"(accA) : "s"(cp), "v"(bA[2 * k]));
            asm("v_pk_fma_f32 %0, %1, %2, %0 op_sel:[0,0,0] op_sel_hi:[0,1,1]"
                : "+v"(accB) : "s"(cp), "v"(bB[2 * k]));
            // odd d = 2k+1: broadcast HI
            asm("v_pk_fma_f32 %0, %1, %2, %0 op_sel:[1,0,0] op_sel_hi:[1,1,1]"
                : "+v"(accA) : "s"(cp), "v"(bA[2 * k + 1]));
            asm("v_pk_fma_f32 %0, %1, %2, %0 op_sel:[1,0,0] op_sel_hi:[1,1,1]"
                : "+v"(accB) : "s"(cp), "v"(bB[2 * k + 1]));
        }
        float4* dst = reinterpret_cast<float4*>(out + (size_t)m * (size_t)n + i);
        *dst = make_float4(accA.x, accA.y, accB.x, accB.y);
    }
}

extern "C" void kernel_launch(void* const* d_in, const int* in_sizes, int n_in,
                              void* d_out, int out_size, void* d_ws, size_t ws_size,
                              hipStream_t stream) {
    const float* x = (const float*)d_in[0];
    const float* a = (const float*)d_in[1];
    float* out = (float*)d_out;
    const int n = in_sizes[0];  // 2097152

    const int threads = 256;
    const int elems_per_block = threads * ELEMS_PER_THREAD;  // 1024
    const int blocks = (n + elems_per_block - 1) / elems_per_block;  // 2048

    cheb_gemm_kernel<<<blocks, threads, 0, stream>>>(x, a, out, n);
}